// Round 9
// baseline (159.010 us; speedup 1.0000x reference)
//
#include <hip/hip_runtime.h>
#include <hip/hip_bf16.h>

typedef __hip_bfloat16 bf16;
typedef __attribute__((ext_vector_type(8))) short s8v;   // 8 bf16 = 4 VGPR (MFMA A/B frag)
typedef __attribute__((ext_vector_type(4))) float f4v;   // MFMA C/D frag

__device__ __forceinline__ ushort f2u(float f) {
    bf16 h = __float2bfloat16(f);
    return *(ushort*)&h;
}

// ---------------------------------------------------------------------------
// B=4, C=256, H=W=64, N=4096. All inputs/outputs fp32; internal bf16.
// ws: Qb  bf16 [16384][32]    @ 0          ( 1 MiB)
//     Kb  bf16 [16384][32]    @ 1048576    ( 1 MiB)
//     Vf  bf16 frag-ordered   @ 2097152    ( 8 MiB)
//     Wf  bf16 frag-ordered   @ 10485760   ( 320 KiB)
// R9 = R7-best attn (128-col phases, V dbuf dist-1, K dist-2, lgkm-only
// barrier) + single change: Ps stride 136 -> 132 ushorts (264B = 66dw = 2
// mod 32 banks; was 4 mod 32 -> 8-way pattern). R8 validated this residue
// class drops conflicts 13x. Phase-size ladder measured: 64c=61.3us,
// 128c=53.4us (best), 256c+single-buf-V=56.7us.
// Vf: element (b,c,n) at b<<20 + (n>>5)*8192 + (c>>4)*512 + ((n>>3)&3)*128
//     + (c&15)*8 + (n&7)  -> MFMA B-frag = contiguous 1KB per wave.
// Wf: element (o,k) at (k>>5)*10240 + (o>>4)*512 + ((k>>3)&3)*128 + (o&15)*8
//     + (k&7)             -> same property.
// MFMA 16x16x32 bf16 layouts (m89/m120-verified):
//   A: lane holds A[m=lane&15][k=(lane>>4)*8+j]
//   B: lane holds B[k=(lane>>4)*8+j][n=lane&15]
//   C/D: lane holds D[row=(lane>>4)*4+r][col=lane&15]
// ---------------------------------------------------------------------------

// Kernel 1: W fp32 -> bf16 frag-order conversion. 80 blocks x 256 thr.
__global__ __launch_bounds__(256) void wcvt_kernel(
    const float* __restrict__ wb, const float* __restrict__ wc,
    const float* __restrict__ wd, ushort* __restrict__ Wf) {
    int f = blockIdx.x * 4 + (threadIdx.x >> 6);   // 0..319
    int l = threadIdx.x & 63;
    int ot = f % 20, kc = f / 20;
    int o = ot * 16 + (l & 15);
    int k0 = kc * 32 + (l >> 4) * 8;
    const float* wr = (o < 32) ? wb + (size_t)o * 512
                    : (o < 64) ? wc + (size_t)(o - 32) * 512
                               : wd + (size_t)(o - 64) * 512;
    float4 f0 = *(const float4*)(wr + k0);
    float4 f1 = *(const float4*)(wr + k0 + 4);
    ushort tmp[8] = {f2u(f0.x), f2u(f0.y), f2u(f0.z), f2u(f0.w),
                     f2u(f1.x), f2u(f1.y), f2u(f1.z), f2u(f1.w)};
    *(uint4*)(Wf + kc * 10240 + ot * 512 + l * 8) = *(uint4*)tmp;
}

// Kernel 2 (unchanged R4): 3x3 avg(/9)+max pooling -> bf16 cat tile in LDS ->
// barrier-free projection K-loop -> Qb/Kb/Vf. 256 blocks (1/CU), 512 thr.
__global__ __launch_bounds__(512, 2) void fused_kernel(
    const float* __restrict__ x, const ushort* __restrict__ Wf,
    const float* __restrict__ bb, const float* __restrict__ bc,
    const float* __restrict__ bd,
    ushort* __restrict__ Qb, ushort* __restrict__ Kb, ushort* __restrict__ Vf) {
    __shared__ __align__(16) char smem[117248];
    float*  Xs   = (float*)smem;              // [3][64][66] fp32 (pool phase)
    ushort* Vls  = (ushort*)smem;             // [256][72]   (epilogue, aliases Xs)
    ushort* catS = (ushort*)(smem + 50688);   // [64][520]  bf16 cat tile

    int tid = threadIdx.x;
    int bid = blockIdx.x;
    int lb = (bid & 7) * 32 + (bid >> 3);     // XCD-chunk swizzle (8x32, bijective)
    int b = lb >> 6, h = lb & 63;
    bool hasU = (h > 0), hasD = (h < 63);

    float4 xr[6];
#define LOADCG(CG)                                                              \
    {                                                                           \
        _Pragma("unroll")                                                       \
        for (int pp = 0; pp < 6; ++pp) {                                        \
            int linear = pp * 512 + tid;                                        \
            int w4 = linear & 15, cs_s = (linear >> 4) & 63, dh = linear >> 10; \
            int hh = h + dh - 1;                                                \
            float4 fv = {0.f, 0.f, 0.f, 0.f};                                   \
            if ((unsigned)hh < 64u)                                             \
                fv = *(const float4*)(x + ((size_t)(b * 256 + (CG) * 64 + cs_s)) * 4096 \
                                      + hh * 64 + w4 * 4);                      \
            xr[pp] = fv;                                                        \
        }                                                                       \
    }
    LOADCG(0)
    #pragma unroll
    for (int cg = 0; cg < 4; ++cg) {
        #pragma unroll
        for (int pp = 0; pp < 6; ++pp) {
            int linear = pp * 512 + tid;
            int w4 = linear & 15, cs_s = (linear >> 4) & 63, dh = linear >> 10;
            float* xp = Xs + (dh * 64 + w4 * 4) * 66 + cs_s;
            xp[0]   = xr[pp].x;
            xp[66]  = xr[pp].y;
            xp[132] = xr[pp].z;
            xp[198] = xr[pp].w;
        }
        __syncthreads();
        if (cg == 0) LOADCG(1)
        else if (cg == 1) LOADCG(2)
        else if (cg == 2) LOADCG(3)
        {
            int cs = tid & 63, wsw = tid >> 6;
            float vs[10], vm[10];
            #pragma unroll
            for (int j = 0; j < 10; ++j) {
                int w = wsw * 8 - 1 + j;
                if ((unsigned)w < 64u) {
                    float u = Xs[w * 66 + cs];
                    float m = Xs[(64 + w) * 66 + cs];
                    float d = Xs[(128 + w) * 66 + cs];
                    vs[j] = u + m + d;
                    float mx = m;
                    if (hasU) mx = fmaxf(mx, u);
                    if (hasD) mx = fmaxf(mx, d);
                    vm[j] = mx;
                } else { vs[j] = 0.f; vm[j] = -3.4e38f; }
            }
            int chb = cg * 64 + cs;
            #pragma unroll
            for (int i = 0; i < 8; ++i) {
                float sum = vs[i] + vs[i + 1] + vs[i + 2];
                float mx  = fmaxf(fmaxf(vm[i], vm[i + 1]), vm[i + 2]);
                catS[(wsw * 8 + i) * 520 + chb]       = f2u(sum * (1.f / 9.f));
                catS[(wsw * 8 + i) * 520 + 256 + chb] = f2u(mx);
            }
        }
        __syncthreads();
    }
#undef LOADCG

    int l = tid & 63, w = tid >> 6;
    int lm = l & 15, q = l >> 4;
    int nc = w & 3, oh = w >> 2;
    f4v pacc[10];
    #pragma unroll
    for (int ot = 0; ot < 10; ++ot)
        #pragma unroll
        for (int i = 0; i < 4; ++i) pacc[ot][i] = 0.f;

    const ushort* wfp = Wf + (oh * 10) * 512 + l * 8;
    const ushort* ap  = catS + (nc * 16 + lm) * 520 + q * 8;
    #pragma unroll 2
    for (int kci = 0; kci < 16; ++kci) {
        s8v Af = *(const s8v*)(ap + kci * 32);
        s8v Bf[10];
        #pragma unroll
        for (int ot = 0; ot < 10; ++ot)
            Bf[ot] = *(const s8v*)(wfp + kci * 10240 + ot * 512);
        #pragma unroll
        for (int ot = 0; ot < 10; ++ot)
            pacc[ot] = __builtin_amdgcn_mfma_f32_16x16x32_bf16(Af, Bf[ot], pacc[ot], 0, 0, 0);
    }

    size_t nrow = (size_t)((b << 12) + h * 64 + nc * 16 + q * 4);
    if (oh == 0) {
        #pragma unroll
        for (int ot = 0; ot < 2; ++ot) {
            int o = ot * 16 + lm;
            float bias = bb[o];
            #pragma unroll
            for (int r = 0; r < 4; ++r)
                Qb[(nrow + r) * 32 + o] = f2u(pacc[ot][r] + bias);
        }
        #pragma unroll
        for (int ot = 2; ot < 4; ++ot) {
            int o = ot * 16 + lm - 32;
            float bias = bc[o];
            #pragma unroll
            for (int r = 0; r < 4; ++r)
                Kb[(nrow + r) * 32 + o] = f2u(pacc[ot][r] + bias);
        }
        #pragma unroll
        for (int ot = 4; ot < 10; ++ot) {
            int c = ot * 16 + lm - 64;
            float bias = bd[c];
            ushort tmp[4];
            #pragma unroll
            for (int r = 0; r < 4; ++r) tmp[r] = f2u(pacc[ot][r] + bias);
            *(uint2*)&Vls[c * 72 + nc * 16 + q * 4] = *(uint2*)tmp;
        }
    } else {
        #pragma unroll
        for (int ot = 0; ot < 10; ++ot) {
            int c = 96 + ot * 16 + lm;
            float bias = bd[c];
            ushort tmp[4];
            #pragma unroll
            for (int r = 0; r < 4; ++r) tmp[r] = f2u(pacc[ot][r] + bias);
            *(uint2*)&Vls[c * 72 + nc * 16 + q * 4] = *(uint2*)tmp;
        }
    }
    __syncthreads();
    {
        size_t vb = ((size_t)b << 20) + (size_t)(h * 2) * 8192 + l * 8;
        #pragma unroll
        for (int i = 0; i < 2; ++i) {
            int cb = w * 2 + i;
            #pragma unroll
            for (int nh = 0; nh < 2; ++nh)
                *(uint4*)(Vf + vb + nh * 8192 + cb * 512)
                    = *(const uint4*)&Vls[(cb * 16 + lm) * 72 + nh * 32 + q * 8];
        }
    }
}

// Kernel 3 (R9 = R7 + Ps stride 132): MFMA flash attention + residual.
// 256 blocks, 512 threads. 128-col KV phases (32 phases). Per wave per phase:
// 4 S-MFMA, 16 exps, 8 Af ds_reads, 32 PV MFMA. Body order: prefetch K(t+2),
// V(t+1) (registers, NOT drained at barrier) -> S(t+1) -> Af ds_reads ->
// exp+Ps write -> PV(t) -> lgkm-only barrier.
__global__ __launch_bounds__(512, 2) void attn_kernel(
    const ushort* __restrict__ Qb, const ushort* __restrict__ Kb,
    const ushort* __restrict__ Vf, const float* __restrict__ x,
    const float* __restrict__ alphap, float* __restrict__ out) {
    __shared__ __align__(16) ushort Ps[2][64][132];   // 264B row = 66dw = 2 mod 32 banks
    __shared__ float Obuf[4][64][17];
    __shared__ float Lpart[4][64];
    __shared__ float Lrow[64];
    int tid = threadIdx.x;
    int l = tid & 63, w = tid >> 6;
    int lm = l & 15, q = l >> 4;
    int nsw = w & 3, kh = w >> 2;
    int bid = blockIdx.x;
    int xcd = bid & 7;
    int b = xcd & 3;
    int midx = (bid >> 3) + ((xcd >> 2) << 5);
    int m0 = midx << 6;
    size_t bN = (size_t)b << 12;

    s8v Qf[2];
    {
        const ushort* qb = Qb + (bN + m0 + kh * 32) * 32;
        Qf[0] = *(const s8v*)(qb + (size_t)(lm) * 32 + q * 8);
        Qf[1] = *(const s8v*)(qb + (size_t)(16 + lm) * 32 + q * 8);
    }
    // K: phase t, chunk c (0/1): row = t*128 + nsw*32 + c*16 + lm
    const ushort* kbp = Kb + (bN + nsw * 32 + lm) * 32 + q * 8;
    // V: phase t, k-slice s (0/1), ch tile ct: group 4t+2kh+s, tile nsw*4+ct
    const ushort* vfp = Vf + ((size_t)b << 20) + (size_t)(2 * kh) * 8192
                        + (nsw * 4) * 512 + l * 8;

    f4v acc[4][4];
    #pragma unroll
    for (int mt = 0; mt < 4; ++mt)
        #pragma unroll
        for (int ct = 0; ct < 4; ++ct)
            #pragma unroll
            for (int i = 0; i < 4; ++i) acc[mt][ct][i] = 0.f;
    float La0 = 0.f, La1 = 0.f;

    // exp+pack+store of a 4-result score group into PDST
#define SCORE_TAIL(S00, S01, S10, S11, PDST)                                      \
    {                                                                             \
        ushort e00[4], e01[4], e10[4], e11[4];                                    \
        _Pragma("unroll")                                                         \
        for (int r = 0; r < 4; ++r) {                                             \
            float f00 = __expf(fminf(S00[r], 60.f));                              \
            float f01 = __expf(fminf(S01[r], 60.f));                              \
            float f10 = __expf(fminf(S10[r], 60.f));                              \
            float f11 = __expf(fminf(S11[r], 60.f));                              \
            La0 += f00 + f10; La1 += f01 + f11;                                   \
            e00[r] = f2u(f00); e01[r] = f2u(f01);                                 \
            e10[r] = f2u(f10); e11[r] = f2u(f11);                                 \
        }                                                                         \
        *(uint2*)&PDST[kh * 32 + lm][nsw * 32 + q * 4]           = *(uint2*)e00;  \
        *(uint2*)&PDST[kh * 32 + 16 + lm][nsw * 32 + q * 4]      = *(uint2*)e01;  \
        *(uint2*)&PDST[kh * 32 + lm][nsw * 32 + 16 + q * 4]      = *(uint2*)e10;  \
        *(uint2*)&PDST[kh * 32 + 16 + lm][nsw * 32 + 16 + q * 4] = *(uint2*)e11;  \
    }

    // prologue: K(0), K(1), V(0); compute S(0) -> Ps[0]
    s8v kfA[2], kfB[2], vfA[8], vfB[8];
    kfA[0] = *(const s8v*)(kbp);
    kfA[1] = *(const s8v*)(kbp + 512);
    kfB[0] = *(const s8v*)(kbp + 4096);
    kfB[1] = *(const s8v*)(kbp + 4096 + 512);
    #pragma unroll
    for (int i = 0; i < 8; ++i)   // i = ct*2 + s
        vfA[i] = *(const s8v*)(vfp + (i >> 1) * 512 + (i & 1) * 8192);
    {
        f4v S00 = {0.f, 0.f, 0.f, 0.f}, S01 = {0.f, 0.f, 0.f, 0.f};
        f4v S10 = {0.f, 0.f, 0.f, 0.f}, S11 = {0.f, 0.f, 0.f, 0.f};
        S00 = __builtin_amdgcn_mfma_f32_16x16x32_bf16(kfA[0], Qf[0], S00, 0, 0, 0);
        S01 = __builtin_amdgcn_mfma_f32_16x16x32_bf16(kfA[0], Qf[1], S01, 0, 0, 0);
        S10 = __builtin_amdgcn_mfma_f32_16x16x32_bf16(kfA[1], Qf[0], S10, 0, 0, 0);
        S11 = __builtin_amdgcn_mfma_f32_16x16x32_bf16(kfA[1], Qf[1], S11, 0, 0, 0);
        SCORE_TAIL(S00, S01, S10, S11, Ps[0])
    }
    __syncthreads();

// Phase(TT): prefetch K(TT+2), V(TT+1) (registers, NOT drained at barrier);
// S(TT+1) MFMAs; Af<-Ps[p]; exp(TT+1)+Ps[1-p] write; PV(TT) x32; lgkm barrier.
#define TILE_BODY(TT, KFS, KFP, VCUR, VNXT)                                       \
    {                                                                             \
        int p = (TT) & 1;                                                         \
        if ((TT) < 30) {                                                          \
            const ushort* kn = kbp + (size_t)((TT) + 2) * 4096;                   \
            KFP[0] = *(const s8v*)kn;                                             \
            KFP[1] = *(const s8v*)(kn + 512);                                     \
        }                                                                         \
        if ((TT) < 31) {                                                          \
            const ushort* vn = vfp + (size_t)((TT) + 1) * 32768;                  \
            _Pragma("unroll")                                                     \
            for (int i = 0; i < 8; ++i)                                           \
                VNXT[i] = *(const s8v*)(vn + (i >> 1) * 512 + (i & 1) * 8192);    \
        }                                                                         \
        f4v S00 = {0.f, 0.f, 0.f, 0.f}, S01 = {0.f, 0.f, 0.f, 0.f};               \
        f4v S10 = {0.f, 0.f, 0.f, 0.f}, S11 = {0.f, 0.f, 0.f, 0.f};               \
        if ((TT) < 31) {                                                          \
            S00 = __builtin_amdgcn_mfma_f32_16x16x32_bf16(KFS[0], Qf[0], S00, 0, 0, 0); \
            S01 = __builtin_amdgcn_mfma_f32_16x16x32_bf16(KFS[0], Qf[1], S01, 0, 0, 0); \
            S10 = __builtin_amdgcn_mfma_f32_16x16x32_bf16(KFS[1], Qf[0], S10, 0, 0, 0); \
            S11 = __builtin_amdgcn_mfma_f32_16x16x32_bf16(KFS[1], Qf[1], S11, 0, 0, 0); \
        }                                                                         \
        s8v Af[4][2];                                                             \
        _Pragma("unroll")                                                         \
        for (int mt = 0; mt < 4; ++mt) {                                          \
            Af[mt][0] = *(const s8v*)&Ps[p][mt * 16 + lm][kh * 64 + q * 8];       \
            Af[mt][1] = *(const s8v*)&Ps[p][mt * 16 + lm][kh * 64 + 32 + q * 8];  \
        }                                                                         \
        if ((TT) < 31) SCORE_TAIL(S00, S01, S10, S11, Ps[1 - p])                  \
        _Pragma("unroll")                                                         \
        for (int ct = 0; ct < 4; ++ct) {                                          \
            _Pragma("unroll")                                                     \
            for (int mt = 0; mt < 4; ++mt) {                                      \
                acc[mt][ct] = __builtin_amdgcn_mfma_f32_16x16x32_bf16(Af[mt][0], VCUR[ct * 2],     acc[mt][ct], 0, 0, 0); \
                acc[mt][ct] = __builtin_amdgcn_mfma_f32_16x16x32_bf16(Af[mt][1], VCUR[ct * 2 + 1], acc[mt][ct], 0, 0, 0); \
            }                                                                     \
        }                                                                         \
        asm volatile("s_waitcnt lgkmcnt(0)\n\ts_barrier" ::: "memory");           \
    }

    for (int t = 0; t < 32; t += 2) {
        TILE_BODY(t,     kfB, kfA, vfA, vfB);
        TILE_BODY(t + 1, kfA, kfB, vfB, vfA);
    }
#undef TILE_BODY
#undef SCORE_TAIL

    // L: reduce over q groups (n-dir), then across nsw waves
    La0 += __shfl_xor(La0, 16, 64); La0 += __shfl_xor(La0, 32, 64);
    La1 += __shfl_xor(La1, 16, 64); La1 += __shfl_xor(La1, 32, 64);
    if (q == 0) {
        Lpart[nsw][kh * 32 + lm]      = La0;
        Lpart[nsw][kh * 32 + 16 + lm] = La1;
    }
    __syncthreads();
    if (tid < 64)
        Lrow[tid] = Lpart[0][tid] + Lpart[1][tid] + Lpart[2][tid] + Lpart[3][tid];
    __syncthreads();
    // combine k-halves through LDS
    #pragma unroll
    for (int ct = 0; ct < 4; ++ct) {
        if (kh == 1) {
            #pragma unroll
            for (int mt = 0; mt < 4; ++mt)
                #pragma unroll
                for (int r = 0; r < 4; ++r)
                    Obuf[nsw][mt * 16 + q * 4 + r][lm] = acc[mt][ct][r];
        }
        __syncthreads();
        if (kh == 0) {
            #pragma unroll
            for (int mt = 0; mt < 4; ++mt)
                #pragma unroll
                for (int r = 0; r < 4; ++r)
                    acc[mt][ct][r] += Obuf[nsw][mt * 16 + q * 4 + r][lm];
        }
        __syncthreads();
    }
    if (kh == 0) {
        float alpha = alphap[0];
        float ra = 1.f - alpha;
        #pragma unroll
        for (int mt = 0; mt < 4; ++mt) {
            float L0 = Lrow[mt * 16 + q * 4 + 0];
            float L1 = Lrow[mt * 16 + q * 4 + 1];
            float L2 = Lrow[mt * 16 + q * 4 + 2];
            float L3 = Lrow[mt * 16 + q * 4 + 3];
            #pragma unroll
            for (int ct = 0; ct < 4; ++ct) {
                int cc = nsw * 64 + ct * 16 + lm;
                size_t base = ((size_t)(b * 256 + cc)) * 4096 + m0 + mt * 16 + q * 4;
                float4 xv = *(const float4*)(x + base);
                float4 ov;
                ov.x = alpha * (acc[mt][ct][0] / L0) + ra * xv.x;
                ov.y = alpha * (acc[mt][ct][1] / L1) + ra * xv.y;
                ov.z = alpha * (acc[mt][ct][2] / L2) + ra * xv.z;
                ov.w = alpha * (acc[mt][ct][3] / L3) + ra * xv.w;
                *(float4*)(out + base) = ov;
            }
        }
    }
}

extern "C" void kernel_launch(void* const* d_in, const int* in_sizes, int n_in,
                              void* d_out, int out_size, void* d_ws, size_t ws_size,
                              hipStream_t stream) {
    const float* x  = (const float*)d_in[0];
    const float* wb = (const float*)d_in[1];
    const float* bb = (const float*)d_in[2];
    const float* wc = (const float*)d_in[3];
    const float* bc = (const float*)d_in[4];
    const float* wd = (const float*)d_in[5];
    const float* bd = (const float*)d_in[6];
    const float* al = (const float*)d_in[7];
    float* out = (float*)d_out;

    char* ws = (char*)d_ws;
    ushort* Qb = (ushort*)ws;                     // 1 MiB
    ushort* Kb = (ushort*)(ws + 1048576);         // 1 MiB
    ushort* Vf = (ushort*)(ws + 2097152);         // 8 MiB (frag-ordered)
    ushort* Wf = (ushort*)(ws + 10485760);        // 320 KiB (frag-ordered)

    wcvt_kernel<<<dim3(80), dim3(256), 0, stream>>>(wb, wc, wd, Wf);
    fused_kernel<<<dim3(256), dim3(512), 0, stream>>>(x, Wf, bb, bc, bd,
                                                      Qb, Kb, Vf);
    attn_kernel<<<dim3(256), dim3(512), 0, stream>>>(Qb, Kb, Vf, x, al, out);
}

// Round 10
// 155.155 us; speedup vs baseline: 1.0248x; 1.0248x over previous
//
#include <hip/hip_runtime.h>
#include <hip/hip_bf16.h>

typedef __hip_bfloat16 bf16;
typedef __attribute__((ext_vector_type(8))) short s8v;   // 8 bf16 = 4 VGPR (MFMA A/B frag)
typedef __attribute__((ext_vector_type(4))) float f4v;   // MFMA C/D frag

__device__ __forceinline__ ushort f2u(float f) {
    bf16 h = __float2bfloat16(f);
    return *(ushort*)&h;
}

// ---------------------------------------------------------------------------
// B=4, C=256, H=W=64, N=4096. All inputs/outputs fp32; internal bf16.
// ws: Qb  bf16 [16384][32]    @ 0          ( 1 MiB)
//     Kb  bf16 [16384][32]    @ 1048576    ( 1 MiB)
//     Vf  bf16 frag-ordered   @ 2097152    ( 8 MiB)
//     Wf  bf16 frag-ordered   @ 10485760   ( 320 KiB)
// R10: attn wave-SPECIALIZATION. Evidence: 288 MFMA/phase = 1440cy floor vs
// 4000cy measured; MfmaUtil 27 + VALUBusy 32 (no pipe saturated); R1/R3/R9
// eliminated occupancy/stagger-with-dist2/conflicts. Diagnosis: lockstep --
// both waves/SIMD run the same segment (VALU then MFMA), segments add.
// Fix: waves 0-3 = scores+exp+L only (VALU-heavy, next phase); waves 4-7 =
// PV only (MFMA-heavy, full K per 64-ch slice). SIMD s hosts one of each ->
// cross-wave pipe overlap (m114). V prefetch: per-ks rolling reload into
// just-freed regs (WAR-ordered after consuming MFMAs -> distance-1 with only
// 64 V VGPRs). No k-half combine needed (PV waves own full K).
// Vf: element (b,c,n) at b<<20 + (n>>5)*8192 + (c>>4)*512 + ((n>>3)&3)*128
//     + (c&15)*8 + (n&7)  -> MFMA B-frag = contiguous 1KB per wave.
// Wf: element (o,k) at (k>>5)*10240 + (o>>4)*512 + ((k>>3)&3)*128 + (o&15)*8
//     + (k&7)             -> same property.
// MFMA 16x16x32 bf16 layouts (m89/m120-verified):
//   A: lane holds A[m=lane&15][k=(lane>>4)*8+j]
//   B: lane holds B[k=(lane>>4)*8+j][n=lane&15]
//   C/D: lane holds D[row=(lane>>4)*4+r][col=lane&15]
// ---------------------------------------------------------------------------

// Kernel 1: W fp32 -> bf16 frag-order conversion. 80 blocks x 256 thr.
__global__ __launch_bounds__(256) void wcvt_kernel(
    const float* __restrict__ wb, const float* __restrict__ wc,
    const float* __restrict__ wd, ushort* __restrict__ Wf) {
    int f = blockIdx.x * 4 + (threadIdx.x >> 6);   // 0..319
    int l = threadIdx.x & 63;
    int ot = f % 20, kc = f / 20;
    int o = ot * 16 + (l & 15);
    int k0 = kc * 32 + (l >> 4) * 8;
    const float* wr = (o < 32) ? wb + (size_t)o * 512
                    : (o < 64) ? wc + (size_t)(o - 32) * 512
                               : wd + (size_t)(o - 64) * 512;
    float4 f0 = *(const float4*)(wr + k0);
    float4 f1 = *(const float4*)(wr + k0 + 4);
    ushort tmp[8] = {f2u(f0.x), f2u(f0.y), f2u(f0.z), f2u(f0.w),
                     f2u(f1.x), f2u(f1.y), f2u(f1.z), f2u(f1.w)};
    *(uint4*)(Wf + kc * 10240 + ot * 512 + l * 8) = *(uint4*)tmp;
}

// Kernel 2 (unchanged R4): 3x3 avg(/9)+max pooling -> bf16 cat tile in LDS ->
// barrier-free projection K-loop -> Qb/Kb/Vf. 256 blocks (1/CU), 512 thr.
__global__ __launch_bounds__(512, 2) void fused_kernel(
    const float* __restrict__ x, const ushort* __restrict__ Wf,
    const float* __restrict__ bb, const float* __restrict__ bc,
    const float* __restrict__ bd,
    ushort* __restrict__ Qb, ushort* __restrict__ Kb, ushort* __restrict__ Vf) {
    __shared__ __align__(16) char smem[117248];
    float*  Xs   = (float*)smem;              // [3][64][66] fp32 (pool phase)
    ushort* Vls  = (ushort*)smem;             // [256][72]   (epilogue, aliases Xs)
    ushort* catS = (ushort*)(smem + 50688);   // [64][520]  bf16 cat tile

    int tid = threadIdx.x;
    int bid = blockIdx.x;
    int lb = (bid & 7) * 32 + (bid >> 3);     // XCD-chunk swizzle (8x32, bijective)
    int b = lb >> 6, h = lb & 63;
    bool hasU = (h > 0), hasD = (h < 63);

    float4 xr[6];
#define LOADCG(CG)                                                              \
    {                                                                           \
        _Pragma("unroll")                                                       \
        for (int pp = 0; pp < 6; ++pp) {                                        \
            int linear = pp * 512 + tid;                                        \
            int w4 = linear & 15, cs_s = (linear >> 4) & 63, dh = linear >> 10; \
            int hh = h + dh - 1;                                                \
            float4 fv = {0.f, 0.f, 0.f, 0.f};                                   \
            if ((unsigned)hh < 64u)                                             \
                fv = *(const float4*)(x + ((size_t)(b * 256 + (CG) * 64 + cs_s)) * 4096 \
                                      + hh * 64 + w4 * 4);                      \
            xr[pp] = fv;                                                        \
        }                                                                       \
    }
    LOADCG(0)
    #pragma unroll
    for (int cg = 0; cg < 4; ++cg) {
        #pragma unroll
        for (int pp = 0; pp < 6; ++pp) {
            int linear = pp * 512 + tid;
            int w4 = linear & 15, cs_s = (linear >> 4) & 63, dh = linear >> 10;
            float* xp = Xs + (dh * 64 + w4 * 4) * 66 + cs_s;
            xp[0]   = xr[pp].x;
            xp[66]  = xr[pp].y;
            xp[132] = xr[pp].z;
            xp[198] = xr[pp].w;
        }
        __syncthreads();
        if (cg == 0) LOADCG(1)
        else if (cg == 1) LOADCG(2)
        else if (cg == 2) LOADCG(3)
        {
            int cs = tid & 63, wsw = tid >> 6;
            float vs[10], vm[10];
            #pragma unroll
            for (int j = 0; j < 10; ++j) {
                int w = wsw * 8 - 1 + j;
                if ((unsigned)w < 64u) {
                    float u = Xs[w * 66 + cs];
                    float m = Xs[(64 + w) * 66 + cs];
                    float d = Xs[(128 + w) * 66 + cs];
                    vs[j] = u + m + d;
                    float mx = m;
                    if (hasU) mx = fmaxf(mx, u);
                    if (hasD) mx = fmaxf(mx, d);
                    vm[j] = mx;
                } else { vs[j] = 0.f; vm[j] = -3.4e38f; }
            }
            int chb = cg * 64 + cs;
            #pragma unroll
            for (int i = 0; i < 8; ++i) {
                float sum = vs[i] + vs[i + 1] + vs[i + 2];
                float mx  = fmaxf(fmaxf(vm[i], vm[i + 1]), vm[i + 2]);
                catS[(wsw * 8 + i) * 520 + chb]       = f2u(sum * (1.f / 9.f));
                catS[(wsw * 8 + i) * 520 + 256 + chb] = f2u(mx);
            }
        }
        __syncthreads();
    }
#undef LOADCG

    int l = tid & 63, w = tid >> 6;
    int lm = l & 15, q = l >> 4;
    int nc = w & 3, oh = w >> 2;
    f4v pacc[10];
    #pragma unroll
    for (int ot = 0; ot < 10; ++ot)
        #pragma unroll
        for (int i = 0; i < 4; ++i) pacc[ot][i] = 0.f;

    const ushort* wfp = Wf + (oh * 10) * 512 + l * 8;
    const ushort* ap  = catS + (nc * 16 + lm) * 520 + q * 8;
    #pragma unroll 2
    for (int kci = 0; kci < 16; ++kci) {
        s8v Af = *(const s8v*)(ap + kci * 32);
        s8v Bf[10];
        #pragma unroll
        for (int ot = 0; ot < 10; ++ot)
            Bf[ot] = *(const s8v*)(wfp + kci * 10240 + ot * 512);
        #pragma unroll
        for (int ot = 0; ot < 10; ++ot)
            pacc[ot] = __builtin_amdgcn_mfma_f32_16x16x32_bf16(Af, Bf[ot], pacc[ot], 0, 0, 0);
    }

    size_t nrow = (size_t)((b << 12) + h * 64 + nc * 16 + q * 4);
    if (oh == 0) {
        #pragma unroll
        for (int ot = 0; ot < 2; ++ot) {
            int o = ot * 16 + lm;
            float bias = bb[o];
            #pragma unroll
            for (int r = 0; r < 4; ++r)
                Qb[(nrow + r) * 32 + o] = f2u(pacc[ot][r] + bias);
        }
        #pragma unroll
        for (int ot = 2; ot < 4; ++ot) {
            int o = ot * 16 + lm - 32;
            float bias = bc[o];
            #pragma unroll
            for (int r = 0; r < 4; ++r)
                Kb[(nrow + r) * 32 + o] = f2u(pacc[ot][r] + bias);
        }
        #pragma unroll
        for (int ot = 4; ot < 10; ++ot) {
            int c = ot * 16 + lm - 64;
            float bias = bd[c];
            ushort tmp[4];
            #pragma unroll
            for (int r = 0; r < 4; ++r) tmp[r] = f2u(pacc[ot][r] + bias);
            *(uint2*)&Vls[c * 72 + nc * 16 + q * 4] = *(uint2*)tmp;
        }
    } else {
        #pragma unroll
        for (int ot = 0; ot < 10; ++ot) {
            int c = 96 + ot * 16 + lm;
            float bias = bd[c];
            ushort tmp[4];
            #pragma unroll
            for (int r = 0; r < 4; ++r) tmp[r] = f2u(pacc[ot][r] + bias);
            *(uint2*)&Vls[c * 72 + nc * 16 + q * 4] = *(uint2*)tmp;
        }
    }
    __syncthreads();
    {
        size_t vb = ((size_t)b << 20) + (size_t)(h * 2) * 8192 + l * 8;
        #pragma unroll
        for (int i = 0; i < 2; ++i) {
            int cb = w * 2 + i;
            #pragma unroll
            for (int nh = 0; nh < 2; ++nh)
                *(uint4*)(Vf + vb + nh * 8192 + cb * 512)
                    = *(const uint4*)&Vls[(cb * 16 + lm) * 72 + nh * 32 + q * 8];
        }
    }
}

// Kernel 3 (R10): wave-specialized flash attention + residual.
// 256 blocks, 512 threads. 128-col phases (32 barriers).
// Waves 0-3 (S role, nsw = w): per phase compute S(t+1) for n-chunk nsw*32,
//   ALL 64 m rows (4 Qf frags), exp -> Ps[1-p]; accumulate La[4]; K dbuf.
// Waves 4-7 (PV role, cq = w-4): per phase 64 PV MFMA for channels cq*64..+64,
//   all m, full phase-K (4 ks); Af from Ps[p]; V rolling reload per ks.
// Barriers OUTSIDE role branches (uniform). lgkm-only barrier in loop.
__global__ __launch_bounds__(512, 2) void attn_kernel(
    const ushort* __restrict__ Qb, const ushort* __restrict__ Kb,
    const ushort* __restrict__ Vf, const float* __restrict__ x,
    const float* __restrict__ alphap, float* __restrict__ out) {
    __shared__ __align__(16) ushort Ps[2][64][132];   // 264B row stride (conflict-free, R9)
    __shared__ float Lpart[4][64];
    __shared__ float Lrow[64];
    int tid = threadIdx.x;
    int l = tid & 63, w = tid >> 6;
    int lm = l & 15, q = l >> 4;
    int bid = blockIdx.x;
    int xcd = bid & 7;
    int b = xcd & 3;
    int midx = (bid >> 3) + ((xcd >> 2) << 5);
    int m0 = midx << 6;
    size_t bN = (size_t)b << 12;

    bool isS = (w < 4);
    int nsw = w & 3;    // S: n-chunk | PV: channel quarter

    // persistent role state (disjoint use; union-allocated)
    s8v Qf[4];                                  // S: Q frags for m halves h=0..3
    s8v kfA[2], kfB[2];                         // S: K double buffer (2 n-16 chunks)
    float La[4] = {0.f, 0.f, 0.f, 0.f};        // S: L accum per m-quarter
    f4v acc[4][4];                              // PV: out acc [mt][ct]
    s8v vf[16];                                 // PV: V frags [ks*4+ct], rolling reload

    const ushort* kbp = Kb + (bN + nsw * 32 + lm) * 32 + q * 8;
    const ushort* vfp = Vf + ((size_t)b << 20) + (nsw * 4) * 512 + l * 8;

    if (isS) {
        #pragma unroll
        for (int h = 0; h < 4; ++h)
            Qf[h] = *(const s8v*)(Qb + (bN + m0 + h * 16 + lm) * 32 + q * 8);
        s8v k00 = *(const s8v*)(kbp);
        s8v k01 = *(const s8v*)(kbp + 512);
        kfB[0] = *(const s8v*)(kbp + 4096);
        kfB[1] = *(const s8v*)(kbp + 4096 + 512);
        // S(0) -> Ps[0]
        #pragma unroll
        for (int c = 0; c < 2; ++c) {
            s8v kc = c ? k01 : k00;
            #pragma unroll
            for (int h = 0; h < 4; ++h) {
                f4v S = {0.f, 0.f, 0.f, 0.f};
                S = __builtin_amdgcn_mfma_f32_16x16x32_bf16(kc, Qf[h], S, 0, 0, 0);
                ushort e[4];
                #pragma unroll
                for (int r = 0; r < 4; ++r) {
                    float f = __expf(fminf(S[r], 60.f));
                    La[h] += f; e[r] = f2u(f);
                }
                *(uint2*)&Ps[0][h * 16 + lm][nsw * 32 + c * 16 + q * 4] = *(uint2*)e;
            }
        }
    } else {
        #pragma unroll
        for (int mt = 0; mt < 4; ++mt)
            #pragma unroll
            for (int ct = 0; ct < 4; ++ct)
                #pragma unroll
                for (int i = 0; i < 4; ++i) acc[mt][ct][i] = 0.f;
        #pragma unroll
        for (int i = 0; i < 16; ++i)   // V(0), i = ks*4+ct
            vf[i] = *(const s8v*)(vfp + (i >> 2) * 8192 + (i & 3) * 512);
    }
    __syncthreads();

// Phase(TT): S waves build S(TT+1)->Ps[1-p], prefetch K(TT+2);
// PV waves: per ks {4 Af ds_reads from Ps[p]; 16 MFMA on vf[ks*4..]; reload
// vf[ks*4..] <- phase TT+1 (WAR after consumption -> dist-1 prefetch)}.
// Uniform lgkm-only barrier (global loads stay in flight).
#define PHASE(TT, KFS, KFP)                                                       \
    {                                                                             \
        int p = (TT) & 1;                                                         \
        if (isS) {                                                                \
            if ((TT) < 30) {                                                      \
                const ushort* kn = kbp + (size_t)((TT) + 2) * 4096;               \
                KFP[0] = *(const s8v*)kn;                                         \
                KFP[1] = *(const s8v*)(kn + 512);                                 \
            }                                                                     \
            if ((TT) < 31) {                                                      \
                _Pragma("unroll")                                                 \
                for (int c = 0; c < 2; ++c) {                                     \
                    _Pragma("unroll")                                             \
                    for (int h = 0; h < 4; ++h) {                                 \
                        f4v S = {0.f, 0.f, 0.f, 0.f};                             \
                        S = __builtin_amdgcn_mfma_f32_16x16x32_bf16(              \
                                KFS[c], Qf[h], S, 0, 0, 0);                       \
                        ushort e[4];                                              \
                        _Pragma("unroll")                                         \
                        for (int r = 0; r < 4; ++r) {                             \
                            float f = __expf(fminf(S[r], 60.f));                  \
                            La[h] += f; e[r] = f2u(f);                            \
                        }                                                         \
                        *(uint2*)&Ps[1 - p][h * 16 + lm][nsw * 32 + c * 16 + q * 4] \
                            = *(uint2*)e;                                         \
                    }                                                             \
                }                                                                 \
            }                                                                     \
        } else {                                                                  \
            const ushort* vn = vfp + (size_t)((TT) + 1) * 32768;                  \
            _Pragma("unroll")                                                     \
            for (int ks = 0; ks < 4; ++ks) {                                      \
                s8v Af[4];                                                        \
                _Pragma("unroll")                                                 \
                for (int mt = 0; mt < 4; ++mt)                                    \
                    Af[mt] = *(const s8v*)&Ps[p][mt * 16 + lm][ks * 32 + q * 8];  \
                _Pragma("unroll")                                                 \
                for (int ct = 0; ct < 4; ++ct) {                                  \
                    _Pragma("unroll")                                             \
                    for (int mt = 0; mt < 4; ++mt)                                \
                        acc[mt][ct] = __builtin_amdgcn_mfma_f32_16x16x32_bf16(    \
                            Af[mt], vf[ks * 4 + ct], acc[mt][ct], 0, 0, 0);       \
                }                                                                 \
                if ((TT) < 31) {                                                  \
                    _Pragma("unroll")                                             \
                    for (int ct = 0; ct < 4; ++ct)                                \
                        vf[ks * 4 + ct] = *(const s8v*)(vn + ks * 8192 + ct * 512); \
                }                                                                 \
            }                                                                     \
        }                                                                         \
        asm volatile("s_waitcnt lgkmcnt(0)\n\ts_barrier" ::: "memory");           \
    }

    for (int t = 0; t < 32; t += 2) {
        PHASE(t,     kfB, kfA);
        PHASE(t + 1, kfA, kfB);
    }
#undef PHASE

    // epilogue: L reduce (S waves) -> Lrow; PV waves write out + residual
    if (isS) {
        #pragma unroll
        for (int h = 0; h < 4; ++h) {
            La[h] += __shfl_xor(La[h], 16, 64);
            La[h] += __shfl_xor(La[h], 32, 64);
        }
        if (q == 0) {
            #pragma unroll
            for (int h = 0; h < 4; ++h)
                Lpart[nsw][h * 16 + lm] = La[h];
        }
    }
    __syncthreads();
    if (tid < 64)
        Lrow[tid] = Lpart[0][tid] + Lpart[1][tid] + Lpart[2][tid] + Lpart[3][tid];
    __syncthreads();
    if (!isS) {
        float alpha = alphap[0];
        float ra = 1.f - alpha;
        #pragma unroll
        for (int mt = 0; mt < 4; ++mt) {
            float L0 = Lrow[mt * 16 + q * 4 + 0];
            float L1 = Lrow[mt * 16 + q * 4 + 1];
            float L2 = Lrow[mt * 16 + q * 4 + 2];
            float L3 = Lrow[mt * 16 + q * 4 + 3];
            #pragma unroll
            for (int ct = 0; ct < 4; ++ct) {
                int cc = nsw * 64 + ct * 16 + lm;
                size_t base = ((size_t)(b * 256 + cc)) * 4096 + m0 + mt * 16 + q * 4;
                float4 xv = *(const float4*)(x + base);
                float4 ov;
                ov.x = alpha * (acc[mt][ct][0] / L0) + ra * xv.x;
                ov.y = alpha * (acc[mt][ct][1] / L1) + ra * xv.y;
                ov.z = alpha * (acc[mt][ct][2] / L2) + ra * xv.z;
                ov.w = alpha * (acc[mt][ct][3] / L3) + ra * xv.w;
                *(float4*)(out + base) = ov;
            }
        }
    }
}

extern "C" void kernel_launch(void* const* d_in, const int* in_sizes, int n_in,
                              void* d_out, int out_size, void* d_ws, size_t ws_size,
                              hipStream_t stream) {
    const float* x  = (const float*)d_in[0];
    const float* wb = (const float*)d_in[1];
    const float* bb = (const float*)d_in[2];
    const float* wc = (const float*)d_in[3];
    const float* bc = (const float*)d_in[4];
    const float* wd = (const float*)d_in[5];
    const float* bd = (const float*)d_in[6];
    const float* al = (const float*)d_in[7];
    float* out = (float*)d_out;

    char* ws = (char*)d_ws;
    ushort* Qb = (ushort*)ws;                     // 1 MiB
    ushort* Kb = (ushort*)(ws + 1048576);         // 1 MiB
    ushort* Vf = (ushort*)(ws + 2097152);         // 8 MiB (frag-ordered)
    ushort* Wf = (ushort*)(ws + 10485760);        // 320 KiB (frag-ordered)

    wcvt_kernel<<<dim3(80), dim3(256), 0, stream>>>(wb, wc, wd, Wf);
    fused_kernel<<<dim3(256), dim3(512), 0, stream>>>(x, Wf, bb, bc, bd,
                                                      Qb, Kb, Vf);
    attn_kernel<<<dim3(256), dim3(512), 0, stream>>>(Qb, Kb, Vf, x, al, out);
}

// Round 11
// 151.607 us; speedup vs baseline: 1.0488x; 1.0234x over previous
//
#include <hip/hip_runtime.h>
#include <hip/hip_bf16.h>

typedef __hip_bfloat16 bf16;
typedef __attribute__((ext_vector_type(8))) short s8v;   // 8 bf16 = 4 VGPR (MFMA A/B frag)
typedef __attribute__((ext_vector_type(4))) float f4v;   // MFMA C/D frag

__device__ __forceinline__ ushort f2u(float f) {
    bf16 h = __float2bfloat16(f);
    return *(ushort*)&h;
}

// ---------------------------------------------------------------------------
// B=4, C=256, H=W=64, N=4096. All inputs/outputs fp32; internal bf16.
// ws: Qb  bf16 [16384][32]    @ 0          ( 1 MiB)
//     Kb  bf16 [16384][32]    @ 1048576    ( 1 MiB)
//     Vf  bf16 frag-ordered   @ 2097152    ( 8 MiB)
//     Wf  bf16 frag-ordered   @ 10485760   ( 320 KiB)
// R11 = R10 wave-specialization x 256-col phases (16 barriers) + T5 setprio.
// R8's 256-col failed on single-buffered V (compiler sank loads to uses);
// R10's rolling per-slice V reload fixes that structurally (WAR-ordered
// reload after the consuming MFMAs -> >=4-slice prefetch distance with only
// 16 live V frags). Waves 0-3: scores+exp+L for next phase (64 cols each,
// K dbuf dist-2). Waves 4-7: PV only (64-ch slice, 8 k-slices/phase, 128
// MFMA). SIMD hosts one of each role -> cross-wave pipe overlap (m114).
// setprio(1) around PV MFMA clusters (T5: role-split prerequisite now met).
// Ps stride 260 ushorts (130dw = 2 mod 32 banks; R8-validated).
// Vf: element (b,c,n) at b<<20 + (n>>5)*8192 + (c>>4)*512 + ((n>>3)&3)*128
//     + (c&15)*8 + (n&7)  -> MFMA B-frag = contiguous 1KB per wave.
// Wf: element (o,k) at (k>>5)*10240 + (o>>4)*512 + ((k>>3)&3)*128 + (o&15)*8
//     + (k&7)             -> same property.
// MFMA 16x16x32 bf16 layouts (m89/m120-verified):
//   A: lane holds A[m=lane&15][k=(lane>>4)*8+j]
//   B: lane holds B[k=(lane>>4)*8+j][n=lane&15]
//   C/D: lane holds D[row=(lane>>4)*4+r][col=lane&15]
// ---------------------------------------------------------------------------

// Kernel 1: W fp32 -> bf16 frag-order conversion. 80 blocks x 256 thr.
__global__ __launch_bounds__(256) void wcvt_kernel(
    const float* __restrict__ wb, const float* __restrict__ wc,
    const float* __restrict__ wd, ushort* __restrict__ Wf) {
    int f = blockIdx.x * 4 + (threadIdx.x >> 6);   // 0..319
    int l = threadIdx.x & 63;
    int ot = f % 20, kc = f / 20;
    int o = ot * 16 + (l & 15);
    int k0 = kc * 32 + (l >> 4) * 8;
    const float* wr = (o < 32) ? wb + (size_t)o * 512
                    : (o < 64) ? wc + (size_t)(o - 32) * 512
                               : wd + (size_t)(o - 64) * 512;
    float4 f0 = *(const float4*)(wr + k0);
    float4 f1 = *(const float4*)(wr + k0 + 4);
    ushort tmp[8] = {f2u(f0.x), f2u(f0.y), f2u(f0.z), f2u(f0.w),
                     f2u(f1.x), f2u(f1.y), f2u(f1.z), f2u(f1.w)};
    *(uint4*)(Wf + kc * 10240 + ot * 512 + l * 8) = *(uint4*)tmp;
}

// Kernel 2 (unchanged R4): 3x3 avg(/9)+max pooling -> bf16 cat tile in LDS ->
// barrier-free projection K-loop -> Qb/Kb/Vf. 256 blocks (1/CU), 512 thr.
__global__ __launch_bounds__(512, 2) void fused_kernel(
    const float* __restrict__ x, const ushort* __restrict__ Wf,
    const float* __restrict__ bb, const float* __restrict__ bc,
    const float* __restrict__ bd,
    ushort* __restrict__ Qb, ushort* __restrict__ Kb, ushort* __restrict__ Vf) {
    __shared__ __align__(16) char smem[117248];
    float*  Xs   = (float*)smem;              // [3][64][66] fp32 (pool phase)
    ushort* Vls  = (ushort*)smem;             // [256][72]   (epilogue, aliases Xs)
    ushort* catS = (ushort*)(smem + 50688);   // [64][520]  bf16 cat tile

    int tid = threadIdx.x;
    int bid = blockIdx.x;
    int lb = (bid & 7) * 32 + (bid >> 3);     // XCD-chunk swizzle (8x32, bijective)
    int b = lb >> 6, h = lb & 63;
    bool hasU = (h > 0), hasD = (h < 63);

    float4 xr[6];
#define LOADCG(CG)                                                              \
    {                                                                           \
        _Pragma("unroll")                                                       \
        for (int pp = 0; pp < 6; ++pp) {                                        \
            int linear = pp * 512 + tid;                                        \
            int w4 = linear & 15, cs_s = (linear >> 4) & 63, dh = linear >> 10; \
            int hh = h + dh - 1;                                                \
            float4 fv = {0.f, 0.f, 0.f, 0.f};                                   \
            if ((unsigned)hh < 64u)                                             \
                fv = *(const float4*)(x + ((size_t)(b * 256 + (CG) * 64 + cs_s)) * 4096 \
                                      + hh * 64 + w4 * 4);                      \
            xr[pp] = fv;                                                        \
        }                                                                       \
    }
    LOADCG(0)
    #pragma unroll
    for (int cg = 0; cg < 4; ++cg) {
        #pragma unroll
        for (int pp = 0; pp < 6; ++pp) {
            int linear = pp * 512 + tid;
            int w4 = linear & 15, cs_s = (linear >> 4) & 63, dh = linear >> 10;
            float* xp = Xs + (dh * 64 + w4 * 4) * 66 + cs_s;
            xp[0]   = xr[pp].x;
            xp[66]  = xr[pp].y;
            xp[132] = xr[pp].z;
            xp[198] = xr[pp].w;
        }
        __syncthreads();
        if (cg == 0) LOADCG(1)
        else if (cg == 1) LOADCG(2)
        else if (cg == 2) LOADCG(3)
        {
            int cs = tid & 63, wsw = tid >> 6;
            float vs[10], vm[10];
            #pragma unroll
            for (int j = 0; j < 10; ++j) {
                int w = wsw * 8 - 1 + j;
                if ((unsigned)w < 64u) {
                    float u = Xs[w * 66 + cs];
                    float m = Xs[(64 + w) * 66 + cs];
                    float d = Xs[(128 + w) * 66 + cs];
                    vs[j] = u + m + d;
                    float mx = m;
                    if (hasU) mx = fmaxf(mx, u);
                    if (hasD) mx = fmaxf(mx, d);
                    vm[j] = mx;
                } else { vs[j] = 0.f; vm[j] = -3.4e38f; }
            }
            int chb = cg * 64 + cs;
            #pragma unroll
            for (int i = 0; i < 8; ++i) {
                float sum = vs[i] + vs[i + 1] + vs[i + 2];
                float mx  = fmaxf(fmaxf(vm[i], vm[i + 1]), vm[i + 2]);
                catS[(wsw * 8 + i) * 520 + chb]       = f2u(sum * (1.f / 9.f));
                catS[(wsw * 8 + i) * 520 + 256 + chb] = f2u(mx);
            }
        }
        __syncthreads();
    }
#undef LOADCG

    int l = tid & 63, w = tid >> 6;
    int lm = l & 15, q = l >> 4;
    int nc = w & 3, oh = w >> 2;
    f4v pacc[10];
    #pragma unroll
    for (int ot = 0; ot < 10; ++ot)
        #pragma unroll
        for (int i = 0; i < 4; ++i) pacc[ot][i] = 0.f;

    const ushort* wfp = Wf + (oh * 10) * 512 + l * 8;
    const ushort* ap  = catS + (nc * 16 + lm) * 520 + q * 8;
    #pragma unroll 2
    for (int kci = 0; kci < 16; ++kci) {
        s8v Af = *(const s8v*)(ap + kci * 32);
        s8v Bf[10];
        #pragma unroll
        for (int ot = 0; ot < 10; ++ot)
            Bf[ot] = *(const s8v*)(wfp + kci * 10240 + ot * 512);
        #pragma unroll
        for (int ot = 0; ot < 10; ++ot)
            pacc[ot] = __builtin_amdgcn_mfma_f32_16x16x32_bf16(Af, Bf[ot], pacc[ot], 0, 0, 0);
    }

    size_t nrow = (size_t)((b << 12) + h * 64 + nc * 16 + q * 4);
    if (oh == 0) {
        #pragma unroll
        for (int ot = 0; ot < 2; ++ot) {
            int o = ot * 16 + lm;
            float bias = bb[o];
            #pragma unroll
            for (int r = 0; r < 4; ++r)
                Qb[(nrow + r) * 32 + o] = f2u(pacc[ot][r] + bias);
        }
        #pragma unroll
        for (int ot = 2; ot < 4; ++ot) {
            int o = ot * 16 + lm - 32;
            float bias = bc[o];
            #pragma unroll
            for (int r = 0; r < 4; ++r)
                Kb[(nrow + r) * 32 + o] = f2u(pacc[ot][r] + bias);
        }
        #pragma unroll
        for (int ot = 4; ot < 10; ++ot) {
            int c = ot * 16 + lm - 64;
            float bias = bd[c];
            ushort tmp[4];
            #pragma unroll
            for (int r = 0; r < 4; ++r) tmp[r] = f2u(pacc[ot][r] + bias);
            *(uint2*)&Vls[c * 72 + nc * 16 + q * 4] = *(uint2*)tmp;
        }
    } else {
        #pragma unroll
        for (int ot = 0; ot < 10; ++ot) {
            int c = 96 + ot * 16 + lm;
            float bias = bd[c];
            ushort tmp[4];
            #pragma unroll
            for (int r = 0; r < 4; ++r) tmp[r] = f2u(pacc[ot][r] + bias);
            *(uint2*)&Vls[c * 72 + nc * 16 + q * 4] = *(uint2*)tmp;
        }
    }
    __syncthreads();
    {
        size_t vb = ((size_t)b << 20) + (size_t)(h * 2) * 8192 + l * 8;
        #pragma unroll
        for (int i = 0; i < 2; ++i) {
            int cb = w * 2 + i;
            #pragma unroll
            for (int nh = 0; nh < 2; ++nh)
                *(uint4*)(Vf + vb + nh * 8192 + cb * 512)
                    = *(const uint4*)&Vls[(cb * 16 + lm) * 72 + nh * 32 + q * 8];
        }
    }
}

// Kernel 3 (R11): wave-specialized flash attention, 256-col phases.
// 256 blocks, 512 threads, 16 barrier phases.
// Waves 0-3 (S role, nsw): S(t+1) for n-chunk nsw*64 (4 x 16-col frags),
//   all 64 m rows; 16 S-MFMA + 64 exps -> Ps[1-p]; K dbuf dist-2.
// Waves 4-7 (PV role, nsw): 128 PV MFMA for channels nsw*64..+64, 8 k-slices;
//   Af from Ps[p]; V rolling reload per slice (slot = s&3, refill with s+4).
// setprio(1) around each 16-MFMA PV cluster (T5). Uniform lgkm-only barrier.
__global__ __launch_bounds__(512, 2) void attn_kernel(
    const ushort* __restrict__ Qb, const ushort* __restrict__ Kb,
    const ushort* __restrict__ Vf, const float* __restrict__ x,
    const float* __restrict__ alphap, float* __restrict__ out) {
    __shared__ __align__(16) ushort Ps[2][64][260];   // 520B row = 130dw = 2 mod 32 banks
    __shared__ float Lpart[4][64];
    __shared__ float Lrow[64];
    int tid = threadIdx.x;
    int l = tid & 63, w = tid >> 6;
    int lm = l & 15, q = l >> 4;
    int bid = blockIdx.x;
    int xcd = bid & 7;
    int b = xcd & 3;
    int midx = (bid >> 3) + ((xcd >> 2) << 5);
    int m0 = midx << 6;
    size_t bN = (size_t)b << 12;

    bool isS = (w < 4);
    int nsw = w & 3;    // S: 64-col n-chunk | PV: channel quarter

    // role state (disjoint; union-allocated by regalloc)
    s8v Qf[4];                                  // S: Q frags m-quarters
    s8v kfA[4], kfB[4];                         // S: K double buffer (4 x 16-col chunks)
    float La[4] = {0.f, 0.f, 0.f, 0.f};        // S: L accum per m-quarter
    f4v acc[4][4];                              // PV: out acc [mt][ct]
    s8v vf[16];                                 // PV: V frags [slot*4+ct], rolling

    const ushort* kbp = Kb + (bN + nsw * 64 + lm) * 32 + q * 8;
    const ushort* vfp = Vf + ((size_t)b << 20) + (nsw * 4) * 512 + l * 8;

    if (isS) {
        #pragma unroll
        for (int h = 0; h < 4; ++h)
            Qf[h] = *(const s8v*)(Qb + (bN + m0 + h * 16 + lm) * 32 + q * 8);
        #pragma unroll
        for (int c = 0; c < 4; ++c) kfA[c] = *(const s8v*)(kbp + c * 512);
        #pragma unroll
        for (int c = 0; c < 4; ++c) kfB[c] = *(const s8v*)(kbp + 8192 + c * 512);
        // S(0) -> Ps[0]
        #pragma unroll
        for (int c = 0; c < 4; ++c) {
            #pragma unroll
            for (int h = 0; h < 4; ++h) {
                f4v S = {0.f, 0.f, 0.f, 0.f};
                S = __builtin_amdgcn_mfma_f32_16x16x32_bf16(kfA[c], Qf[h], S, 0, 0, 0);
                ushort e[4];
                #pragma unroll
                for (int r = 0; r < 4; ++r) {
                    float f = __expf(fminf(S[r], 60.f));
                    La[h] += f; e[r] = f2u(f);
                }
                *(uint2*)&Ps[0][h * 16 + lm][nsw * 64 + c * 16 + q * 4] = *(uint2*)e;
            }
        }
    } else {
        #pragma unroll
        for (int mt = 0; mt < 4; ++mt)
            #pragma unroll
            for (int ct = 0; ct < 4; ++ct)
                #pragma unroll
                for (int i = 0; i < 4; ++i) acc[mt][ct][i] = 0.f;
        #pragma unroll
        for (int i = 0; i < 16; ++i)   // V slices 0..3 of phase 0
            vf[i] = *(const s8v*)(vfp + (i >> 2) * 8192 + (i & 3) * 512);
    }
    __syncthreads();

// Phase(TT): S waves build S(TT+1)->Ps[1-p], prefetch K(TT+2).
// PV waves: per slice s (0..7) { 4 Af ds_reads from Ps[p]; setprio(1);
// 16 MFMA on vf[slot]; setprio(0); reload vf[slot] <- slice s+4 (contiguous:
// spills into phase TT+1 for s>=4) }. Uniform lgkm-only barrier.
#define PHASE(TT, KFS, KFP)                                                       \
    {                                                                             \
        int p = (TT) & 1;                                                         \
        if (isS) {                                                                \
            if ((TT) < 14) {                                                      \
                const ushort* kn = kbp + (size_t)((TT) + 2) * 8192;               \
                _Pragma("unroll")                                                 \
                for (int c = 0; c < 4; ++c) KFP[c] = *(const s8v*)(kn + c * 512); \
            }                                                                     \
            if ((TT) < 15) {                                                      \
                _Pragma("unroll")                                                 \
                for (int c = 0; c < 4; ++c) {                                     \
                    _Pragma("unroll")                                             \
                    for (int h = 0; h < 4; ++h) {                                 \
                        f4v S = {0.f, 0.f, 0.f, 0.f};                             \
                        S = __builtin_amdgcn_mfma_f32_16x16x32_bf16(              \
                                KFS[c], Qf[h], S, 0, 0, 0);                       \
                        ushort e[4];                                              \
                        _Pragma("unroll")                                         \
                        for (int r = 0; r < 4; ++r) {                             \
                            float f = __expf(fminf(S[r], 60.f));                  \
                            La[h] += f; e[r] = f2u(f);                            \
                        }                                                         \
                        *(uint2*)&Ps[1 - p][h * 16 + lm][nsw * 64 + c * 16 + q * 4] \
                            = *(uint2*)e;                                         \
                    }                                                             \
                }                                                                 \
            }                                                                     \
        } else {                                                                  \
            const ushort* vbase = vfp + (size_t)(TT) * 65536;                     \
            _Pragma("unroll")                                                     \
            for (int s = 0; s < 8; ++s) {                                         \
                int slot = s & 3;                                                 \
                s8v Af[4];                                                        \
                _Pragma("unroll")                                                 \
                for (int mt = 0; mt < 4; ++mt)                                    \
                    Af[mt] = *(const s8v*)&Ps[p][mt * 16 + lm][s * 32 + q * 8];   \
                __builtin_amdgcn_s_setprio(1);                                    \
                _Pragma("unroll")                                                 \
                for (int ct = 0; ct < 4; ++ct) {                                  \
                    _Pragma("unroll")                                             \
                    for (int mt = 0; mt < 4; ++mt)                                \
                        acc[mt][ct] = __builtin_amdgcn_mfma_f32_16x16x32_bf16(    \
                            Af[mt], vf[slot * 4 + ct], acc[mt][ct], 0, 0, 0);     \
                }                                                                 \
                __builtin_amdgcn_s_setprio(0);                                    \
                if (s < 4 || (TT) < 15) {                                         \
                    const ushort* vn = vbase + (size_t)(s + 4) * 8192;            \
                    _Pragma("unroll")                                             \
                    for (int ct = 0; ct < 4; ++ct)                                \
                        vf[slot * 4 + ct] = *(const s8v*)(vn + ct * 512);         \
                }                                                                 \
            }                                                                     \
        }                                                                         \
        asm volatile("s_waitcnt lgkmcnt(0)\n\ts_barrier" ::: "memory");           \
    }

    for (int t = 0; t < 16; t += 2) {
        PHASE(t,     kfB, kfA);
        PHASE(t + 1, kfA, kfB);
    }
#undef PHASE

    // epilogue: L reduce (S waves) -> Lrow; PV waves write out + residual
    if (isS) {
        #pragma unroll
        for (int h = 0; h < 4; ++h) {
            La[h] += __shfl_xor(La[h], 16, 64);
            La[h] += __shfl_xor(La[h], 32, 64);
        }
        if (q == 0) {
            #pragma unroll
            for (int h = 0; h < 4; ++h)
                Lpart[nsw][h * 16 + lm] = La[h];
        }
    }
    __syncthreads();
    if (tid < 64)
        Lrow[tid] = Lpart[0][tid] + Lpart[1][tid] + Lpart[2][tid] + Lpart[3][tid];
    __syncthreads();
    if (!isS) {
        float alpha = alphap[0];
        float ra = 1.f - alpha;
        #pragma unroll
        for (int mt = 0; mt < 4; ++mt) {
            float L0 = Lrow[mt * 16 + q * 4 + 0];
            float L1 = Lrow[mt * 16 + q * 4 + 1];
            float L2 = Lrow[mt * 16 + q * 4 + 2];
            float L3 = Lrow[mt * 16 + q * 4 + 3];
            #pragma unroll
            for (int ct = 0; ct < 4; ++ct) {
                int cc = nsw * 64 + ct * 16 + lm;
                size_t base = ((size_t)(b * 256 + cc)) * 4096 + m0 + mt * 16 + q * 4;
                float4 xv = *(const float4*)(x + base);
                float4 ov;
                ov.x = alpha * (acc[mt][ct][0] / L0) + ra * xv.x;
                ov.y = alpha * (acc[mt][ct][1] / L1) + ra * xv.y;
                ov.z = alpha * (acc[mt][ct][2] / L2) + ra * xv.z;
                ov.w = alpha * (acc[mt][ct][3] / L3) + ra * xv.w;
                *(float4*)(out + base) = ov;
            }
        }
    }
}

extern "C" void kernel_launch(void* const* d_in, const int* in_sizes, int n_in,
                              void* d_out, int out_size, void* d_ws, size_t ws_size,
                              hipStream_t stream) {
    const float* x  = (const float*)d_in[0];
    const float* wb = (const float*)d_in[1];
    const float* bb = (const float*)d_in[2];
    const float* wc = (const float*)d_in[3];
    const float* bc = (const float*)d_in[4];
    const float* wd = (const float*)d_in[5];
    const float* bd = (const float*)d_in[6];
    const float* al = (const float*)d_in[7];
    float* out = (float*)d_out;

    char* ws = (char*)d_ws;
    ushort* Qb = (ushort*)ws;                     // 1 MiB
    ushort* Kb = (ushort*)(ws + 1048576);         // 1 MiB
    ushort* Vf = (ushort*)(ws + 2097152);         // 8 MiB (frag-ordered)
    ushort* Wf = (ushort*)(ws + 10485760);        // 320 KiB (frag-ordered)

    wcvt_kernel<<<dim3(80), dim3(256), 0, stream>>>(wb, wc, wd, Wf);
    fused_kernel<<<dim3(256), dim3(512), 0, stream>>>(x, Wf, bb, bc, bd,
                                                      Qb, Kb, Vf);
    attn_kernel<<<dim3(256), dim3(512), 0, stream>>>(Qb, Kb, Vf, x, al, out);
}

// Round 12
// 151.240 us; speedup vs baseline: 1.0514x; 1.0024x over previous
//
#include <hip/hip_runtime.h>
#include <hip/hip_bf16.h>

typedef __hip_bfloat16 bf16;
typedef __attribute__((ext_vector_type(8))) short s8v;   // 8 bf16 = 4 VGPR (MFMA A/B frag)
typedef __attribute__((ext_vector_type(4))) float f4v;   // MFMA C/D frag

__device__ __forceinline__ ushort f2u(float f) {
    bf16 h = __float2bfloat16(f);
    return *(ushort*)&h;
}

// ---------------------------------------------------------------------------
// B=4, C=256, H=W=64, N=4096. All inputs/outputs fp32; internal bf16.
// ws: Qb  bf16 [16384][32]    @ 0          ( 1 MiB)
//     Kb  bf16 [16384][32]    @ 1048576    ( 1 MiB)
//     Vf  bf16 frag-ordered   @ 2097152    ( 8 MiB)
//     Wf  bf16 frag-ordered   @ 10485760   ( 320 KiB)
// R12 = R11 + Af software pipeline in the PV role: slice s issues slice
// s+1's 4 ds_reads BEFORE its 16-MFMA cluster (ping-pong Af regs) -> the
// ~120cy lgkm stall per slice is hidden under MFMA issue. Ladder so far:
// 64c=61.3 / 128c=53.4 / 128c-spec=49.5 / 256c-spec=47.3. Per-phase hole
// ~2,300cy is ds-latency-shaped (MfmaUtil 31 + VALUBusy 35, conflicts 0).
// Vf: element (b,c,n) at b<<20 + (n>>5)*8192 + (c>>4)*512 + ((n>>3)&3)*128
//     + (c&15)*8 + (n&7)  -> MFMA B-frag = contiguous 1KB per wave.
// Wf: element (o,k) at (k>>5)*10240 + (o>>4)*512 + ((k>>3)&3)*128 + (o&15)*8
//     + (k&7)             -> same property.
// MFMA 16x16x32 bf16 layouts (m89/m120-verified):
//   A: lane holds A[m=lane&15][k=(lane>>4)*8+j]
//   B: lane holds B[k=(lane>>4)*8+j][n=lane&15]
//   C/D: lane holds D[row=(lane>>4)*4+r][col=lane&15]
// ---------------------------------------------------------------------------

// Kernel 1: W fp32 -> bf16 frag-order conversion. 80 blocks x 256 thr.
__global__ __launch_bounds__(256) void wcvt_kernel(
    const float* __restrict__ wb, const float* __restrict__ wc,
    const float* __restrict__ wd, ushort* __restrict__ Wf) {
    int f = blockIdx.x * 4 + (threadIdx.x >> 6);   // 0..319
    int l = threadIdx.x & 63;
    int ot = f % 20, kc = f / 20;
    int o = ot * 16 + (l & 15);
    int k0 = kc * 32 + (l >> 4) * 8;
    const float* wr = (o < 32) ? wb + (size_t)o * 512
                    : (o < 64) ? wc + (size_t)(o - 32) * 512
                               : wd + (size_t)(o - 64) * 512;
    float4 f0 = *(const float4*)(wr + k0);
    float4 f1 = *(const float4*)(wr + k0 + 4);
    ushort tmp[8] = {f2u(f0.x), f2u(f0.y), f2u(f0.z), f2u(f0.w),
                     f2u(f1.x), f2u(f1.y), f2u(f1.z), f2u(f1.w)};
    *(uint4*)(Wf + kc * 10240 + ot * 512 + l * 8) = *(uint4*)tmp;
}

// Kernel 2 (unchanged R4): 3x3 avg(/9)+max pooling -> bf16 cat tile in LDS ->
// barrier-free projection K-loop -> Qb/Kb/Vf. 256 blocks (1/CU), 512 thr.
__global__ __launch_bounds__(512, 2) void fused_kernel(
    const float* __restrict__ x, const ushort* __restrict__ Wf,
    const float* __restrict__ bb, const float* __restrict__ bc,
    const float* __restrict__ bd,
    ushort* __restrict__ Qb, ushort* __restrict__ Kb, ushort* __restrict__ Vf) {
    __shared__ __align__(16) char smem[117248];
    float*  Xs   = (float*)smem;              // [3][64][66] fp32 (pool phase)
    ushort* Vls  = (ushort*)smem;             // [256][72]   (epilogue, aliases Xs)
    ushort* catS = (ushort*)(smem + 50688);   // [64][520]  bf16 cat tile

    int tid = threadIdx.x;
    int bid = blockIdx.x;
    int lb = (bid & 7) * 32 + (bid >> 3);     // XCD-chunk swizzle (8x32, bijective)
    int b = lb >> 6, h = lb & 63;
    bool hasU = (h > 0), hasD = (h < 63);

    float4 xr[6];
#define LOADCG(CG)                                                              \
    {                                                                           \
        _Pragma("unroll")                                                       \
        for (int pp = 0; pp < 6; ++pp) {                                        \
            int linear = pp * 512 + tid;                                        \
            int w4 = linear & 15, cs_s = (linear >> 4) & 63, dh = linear >> 10; \
            int hh = h + dh - 1;                                                \
            float4 fv = {0.f, 0.f, 0.f, 0.f};                                   \
            if ((unsigned)hh < 64u)                                             \
                fv = *(const float4*)(x + ((size_t)(b * 256 + (CG) * 64 + cs_s)) * 4096 \
                                      + hh * 64 + w4 * 4);                      \
            xr[pp] = fv;                                                        \
        }                                                                       \
    }
    LOADCG(0)
    #pragma unroll
    for (int cg = 0; cg < 4; ++cg) {
        #pragma unroll
        for (int pp = 0; pp < 6; ++pp) {
            int linear = pp * 512 + tid;
            int w4 = linear & 15, cs_s = (linear >> 4) & 63, dh = linear >> 10;
            float* xp = Xs + (dh * 64 + w4 * 4) * 66 + cs_s;
            xp[0]   = xr[pp].x;
            xp[66]  = xr[pp].y;
            xp[132] = xr[pp].z;
            xp[198] = xr[pp].w;
        }
        __syncthreads();
        if (cg == 0) LOADCG(1)
        else if (cg == 1) LOADCG(2)
        else if (cg == 2) LOADCG(3)
        {
            int cs = tid & 63, wsw = tid >> 6;
            float vs[10], vm[10];
            #pragma unroll
            for (int j = 0; j < 10; ++j) {
                int w = wsw * 8 - 1 + j;
                if ((unsigned)w < 64u) {
                    float u = Xs[w * 66 + cs];
                    float m = Xs[(64 + w) * 66 + cs];
                    float d = Xs[(128 + w) * 66 + cs];
                    vs[j] = u + m + d;
                    float mx = m;
                    if (hasU) mx = fmaxf(mx, u);
                    if (hasD) mx = fmaxf(mx, d);
                    vm[j] = mx;
                } else { vs[j] = 0.f; vm[j] = -3.4e38f; }
            }
            int chb = cg * 64 + cs;
            #pragma unroll
            for (int i = 0; i < 8; ++i) {
                float sum = vs[i] + vs[i + 1] + vs[i + 2];
                float mx  = fmaxf(fmaxf(vm[i], vm[i + 1]), vm[i + 2]);
                catS[(wsw * 8 + i) * 520 + chb]       = f2u(sum * (1.f / 9.f));
                catS[(wsw * 8 + i) * 520 + 256 + chb] = f2u(mx);
            }
        }
        __syncthreads();
    }
#undef LOADCG

    int l = tid & 63, w = tid >> 6;
    int lm = l & 15, q = l >> 4;
    int nc = w & 3, oh = w >> 2;
    f4v pacc[10];
    #pragma unroll
    for (int ot = 0; ot < 10; ++ot)
        #pragma unroll
        for (int i = 0; i < 4; ++i) pacc[ot][i] = 0.f;

    const ushort* wfp = Wf + (oh * 10) * 512 + l * 8;
    const ushort* ap  = catS + (nc * 16 + lm) * 520 + q * 8;
    #pragma unroll 2
    for (int kci = 0; kci < 16; ++kci) {
        s8v Af = *(const s8v*)(ap + kci * 32);
        s8v Bf[10];
        #pragma unroll
        for (int ot = 0; ot < 10; ++ot)
            Bf[ot] = *(const s8v*)(wfp + kci * 10240 + ot * 512);
        #pragma unroll
        for (int ot = 0; ot < 10; ++ot)
            pacc[ot] = __builtin_amdgcn_mfma_f32_16x16x32_bf16(Af, Bf[ot], pacc[ot], 0, 0, 0);
    }

    size_t nrow = (size_t)((b << 12) + h * 64 + nc * 16 + q * 4);
    if (oh == 0) {
        #pragma unroll
        for (int ot = 0; ot < 2; ++ot) {
            int o = ot * 16 + lm;
            float bias = bb[o];
            #pragma unroll
            for (int r = 0; r < 4; ++r)
                Qb[(nrow + r) * 32 + o] = f2u(pacc[ot][r] + bias);
        }
        #pragma unroll
        for (int ot = 2; ot < 4; ++ot) {
            int o = ot * 16 + lm - 32;
            float bias = bc[o];
            #pragma unroll
            for (int r = 0; r < 4; ++r)
                Kb[(nrow + r) * 32 + o] = f2u(pacc[ot][r] + bias);
        }
        #pragma unroll
        for (int ot = 4; ot < 10; ++ot) {
            int c = ot * 16 + lm - 64;
            float bias = bd[c];
            ushort tmp[4];
            #pragma unroll
            for (int r = 0; r < 4; ++r) tmp[r] = f2u(pacc[ot][r] + bias);
            *(uint2*)&Vls[c * 72 + nc * 16 + q * 4] = *(uint2*)tmp;
        }
    } else {
        #pragma unroll
        for (int ot = 0; ot < 10; ++ot) {
            int c = 96 + ot * 16 + lm;
            float bias = bd[c];
            ushort tmp[4];
            #pragma unroll
            for (int r = 0; r < 4; ++r) tmp[r] = f2u(pacc[ot][r] + bias);
            *(uint2*)&Vls[c * 72 + nc * 16 + q * 4] = *(uint2*)tmp;
        }
    }
    __syncthreads();
    {
        size_t vb = ((size_t)b << 20) + (size_t)(h * 2) * 8192 + l * 8;
        #pragma unroll
        for (int i = 0; i < 2; ++i) {
            int cb = w * 2 + i;
            #pragma unroll
            for (int nh = 0; nh < 2; ++nh)
                *(uint4*)(Vf + vb + nh * 8192 + cb * 512)
                    = *(const uint4*)&Vls[(cb * 16 + lm) * 72 + nh * 32 + q * 8];
        }
    }
}

// Kernel 3 (R12): wave-specialized flash attention, 256-col phases, Af-piped.
// 256 blocks, 512 threads, 16 barrier phases.
// Waves 0-3 (S role): S(t+1) for n-chunk nsw*64, all 64 m rows; K dbuf.
// Waves 4-7 (PV role): 128 PV MFMA (64-ch slice, 8 k-slices); Af ping-pong
//   prefetch (slice s issues s+1's ds_reads before its MFMA cluster);
//   V rolling reload (slot = s&3, refill slice s+4). setprio around MFMA.
// Uniform lgkm-only barrier. Ps stride 260 (conflict-free, R8-validated).
__global__ __launch_bounds__(512, 2) void attn_kernel(
    const ushort* __restrict__ Qb, const ushort* __restrict__ Kb,
    const ushort* __restrict__ Vf, const float* __restrict__ x,
    const float* __restrict__ alphap, float* __restrict__ out) {
    __shared__ __align__(16) ushort Ps[2][64][260];   // 520B row = 130dw = 2 mod 32 banks
    __shared__ float Lpart[4][64];
    __shared__ float Lrow[64];
    int tid = threadIdx.x;
    int l = tid & 63, w = tid >> 6;
    int lm = l & 15, q = l >> 4;
    int bid = blockIdx.x;
    int xcd = bid & 7;
    int b = xcd & 3;
    int midx = (bid >> 3) + ((xcd >> 2) << 5);
    int m0 = midx << 6;
    size_t bN = (size_t)b << 12;

    bool isS = (w < 4);
    int nsw = w & 3;    // S: 64-col n-chunk | PV: channel quarter

    // role state (disjoint; union-allocated by regalloc)
    s8v Qf[4];                                  // S: Q frags m-quarters
    s8v kfA[4], kfB[4];                         // S: K double buffer (4 x 16-col chunks)
    float La[4] = {0.f, 0.f, 0.f, 0.f};        // S: L accum per m-quarter
    f4v acc[4][4];                              // PV: out acc [mt][ct]
    s8v vf[16];                                 // PV: V frags [slot*4+ct], rolling

    const ushort* kbp = Kb + (bN + nsw * 64 + lm) * 32 + q * 8;
    const ushort* vfp = Vf + ((size_t)b << 20) + (nsw * 4) * 512 + l * 8;

    if (isS) {
        #pragma unroll
        for (int h = 0; h < 4; ++h)
            Qf[h] = *(const s8v*)(Qb + (bN + m0 + h * 16 + lm) * 32 + q * 8);
        #pragma unroll
        for (int c = 0; c < 4; ++c) kfA[c] = *(const s8v*)(kbp + c * 512);
        #pragma unroll
        for (int c = 0; c < 4; ++c) kfB[c] = *(const s8v*)(kbp + 8192 + c * 512);
        // S(0) -> Ps[0]
        #pragma unroll
        for (int c = 0; c < 4; ++c) {
            #pragma unroll
            for (int h = 0; h < 4; ++h) {
                f4v S = {0.f, 0.f, 0.f, 0.f};
                S = __builtin_amdgcn_mfma_f32_16x16x32_bf16(kfA[c], Qf[h], S, 0, 0, 0);
                ushort e[4];
                #pragma unroll
                for (int r = 0; r < 4; ++r) {
                    float f = __expf(fminf(S[r], 60.f));
                    La[h] += f; e[r] = f2u(f);
                }
                *(uint2*)&Ps[0][h * 16 + lm][nsw * 64 + c * 16 + q * 4] = *(uint2*)e;
            }
        }
    } else {
        #pragma unroll
        for (int mt = 0; mt < 4; ++mt)
            #pragma unroll
            for (int ct = 0; ct < 4; ++ct)
                #pragma unroll
                for (int i = 0; i < 4; ++i) acc[mt][ct][i] = 0.f;
        #pragma unroll
        for (int i = 0; i < 16; ++i)   // V slices 0..3 of phase 0
            vf[i] = *(const s8v*)(vfp + (i >> 2) * 8192 + (i & 3) * 512);
    }
    __syncthreads();

// Phase(TT): S waves build S(TT+1)->Ps[1-p], prefetch K(TT+2).
// PV waves: Af ping-pong pipeline over 8 slices: preload Af(0); per slice s
// { issue Af(s+1) ds_reads; setprio(1); 16 MFMA on Af(s) x vf[slot];
// setprio(0); reload vf[slot] <- slice s+4 }. Uniform lgkm-only barrier.
#define PHASE(TT, KFS, KFP)                                                       \
    {                                                                             \
        int p = (TT) & 1;                                                         \
        if (isS) {                                                                \
            if ((TT) < 14) {                                                      \
                const ushort* kn = kbp + (size_t)((TT) + 2) * 8192;               \
                _Pragma("unroll")                                                 \
                for (int c = 0; c < 4; ++c) KFP[c] = *(const s8v*)(kn + c * 512); \
            }                                                                     \
            if ((TT) < 15) {                                                      \
                _Pragma("unroll")                                                 \
                for (int c = 0; c < 4; ++c) {                                     \
                    _Pragma("unroll")                                             \
                    for (int h = 0; h < 4; ++h) {                                 \
                        f4v S = {0.f, 0.f, 0.f, 0.f};                             \
                        S = __builtin_amdgcn_mfma_f32_16x16x32_bf16(              \
                                KFS[c], Qf[h], S, 0, 0, 0);                       \
                        ushort e[4];                                              \
                        _Pragma("unroll")                                         \
                        for (int r = 0; r < 4; ++r) {                             \
                            float f = __expf(fminf(S[r], 60.f));                  \
                            La[h] += f; e[r] = f2u(f);                            \
                        }                                                         \
                        *(uint2*)&Ps[1 - p][h * 16 + lm][nsw * 64 + c * 16 + q * 4] \
                            = *(uint2*)e;                                         \
                    }                                                             \
                }                                                                 \
            }                                                                     \
        } else {                                                                  \
            const ushort* vbase = vfp + (size_t)(TT) * 65536;                     \
            s8v Afp[2][4];                                                        \
            _Pragma("unroll")                                                     \
            for (int mt = 0; mt < 4; ++mt)                                        \
                Afp[0][mt] = *(const s8v*)&Ps[p][mt * 16 + lm][q * 8];            \
            _Pragma("unroll")                                                     \
            for (int s = 0; s < 8; ++s) {                                         \
                int cb = s & 1, nb = cb ^ 1;                                      \
                if (s < 7) {                                                      \
                    _Pragma("unroll")                                             \
                    for (int mt = 0; mt < 4; ++mt)                                \
                        Afp[nb][mt] = *(const s8v*)                               \
                            &Ps[p][mt * 16 + lm][(s + 1) * 32 + q * 8];           \
                }                                                                 \
                int slot = s & 3;                                                 \
                __builtin_amdgcn_s_setprio(1);                                    \
                _Pragma("unroll")                                                 \
                for (int ct = 0; ct < 4; ++ct) {                                  \
                    _Pragma("unroll")                                             \
                    for (int mt = 0; mt < 4; ++mt)                                \
                        acc[mt][ct] = __builtin_amdgcn_mfma_f32_16x16x32_bf16(    \
                            Afp[cb][mt], vf[slot * 4 + ct], acc[mt][ct], 0, 0, 0);\
                }                                                                 \
                __builtin_amdgcn_s_setprio(0);                                    \
                if (s < 4 || (TT) < 15) {                                         \
                    const ushort* vn = vbase + (size_t)(s + 4) * 8192;            \
                    _Pragma("unroll")                                             \
                    for (int ct = 0; ct < 4; ++ct)                                \
                        vf[slot * 4 + ct] = *(const s8v*)(vn + ct * 512);         \
                }                                                                 \
            }                                                                     \
        }                                                                         \
        asm volatile("s_waitcnt lgkmcnt(0)\n\ts_barrier" ::: "memory");           \
    }

    for (int t = 0; t < 16; t += 2) {
        PHASE(t,     kfB, kfA);
        PHASE(t + 1, kfA, kfB);
    }
#undef PHASE

    // epilogue: L reduce (S waves) -> Lrow; PV waves write out + residual
    if (isS) {
        #pragma unroll
        for (int h = 0; h < 4; ++h) {
            La[h] += __shfl_xor(La[h], 16, 64);
            La[h] += __shfl_xor(La[h], 32, 64);
        }
        if (q == 0) {
            #pragma unroll
            for (int h = 0; h < 4; ++h)
                Lpart[nsw][h * 16 + lm] = La[h];
        }
    }
    __syncthreads();
    if (tid < 64)
        Lrow[tid] = Lpart[0][tid] + Lpart[1][tid] + Lpart[2][tid] + Lpart[3][tid];
    __syncthreads();
    if (!isS) {
        float alpha = alphap[0];
        float ra = 1.f - alpha;
        #pragma unroll
        for (int mt = 0; mt < 4; ++mt) {
            float L0 = Lrow[mt * 16 + q * 4 + 0];
            float L1 = Lrow[mt * 16 + q * 4 + 1];
            float L2 = Lrow[mt * 16 + q * 4 + 2];
            float L3 = Lrow[mt * 16 + q * 4 + 3];
            #pragma unroll
            for (int ct = 0; ct < 4; ++ct) {
                int cc = nsw * 64 + ct * 16 + lm;
                size_t base = ((size_t)(b * 256 + cc)) * 4096 + m0 + mt * 16 + q * 4;
                float4 xv = *(const float4*)(x + base);
                float4 ov;
                ov.x = alpha * (acc[mt][ct][0] / L0) + ra * xv.x;
                ov.y = alpha * (acc[mt][ct][1] / L1) + ra * xv.y;
                ov.z = alpha * (acc[mt][ct][2] / L2) + ra * xv.z;
                ov.w = alpha * (acc[mt][ct][3] / L3) + ra * xv.w;
                *(float4*)(out + base) = ov;
            }
        }
    }
}

extern "C" void kernel_launch(void* const* d_in, const int* in_sizes, int n_in,
                              void* d_out, int out_size, void* d_ws, size_t ws_size,
                              hipStream_t stream) {
    const float* x  = (const float*)d_in[0];
    const float* wb = (const float*)d_in[1];
    const float* bb = (const float*)d_in[2];
    const float* wc = (const float*)d_in[3];
    const float* bc = (const float*)d_in[4];
    const float* wd = (const float*)d_in[5];
    const float* bd = (const float*)d_in[6];
    const float* al = (const float*)d_in[7];
    float* out = (float*)d_out;

    char* ws = (char*)d_ws;
    ushort* Qb = (ushort*)ws;                     // 1 MiB
    ushort* Kb = (ushort*)(ws + 1048576);         // 1 MiB
    ushort* Vf = (ushort*)(ws + 2097152);         // 8 MiB (frag-ordered)
    ushort* Wf = (ushort*)(ws + 10485760);        // 320 KiB (frag-ordered)

    wcvt_kernel<<<dim3(80), dim3(256), 0, stream>>>(wb, wc, wd, Wf);
    fused_kernel<<<dim3(256), dim3(512), 0, stream>>>(x, Wf, bb, bc, bd,
                                                      Qb, Kb, Vf);
    attn_kernel<<<dim3(256), dim3(512), 0, stream>>>(Qb, Kb, Vf, x, al, out);
}